// Round 12
// baseline (1671.125 us; speedup 1.0000x reference)
//
#include <hip/hip_runtime.h>
#include <hip/hip_bf16.h>
#include <stdint.h>

// ---------------------------------------------------------------------------
// EquilibriumPropagationNet free-phase settle, fused, split-bf16 precision.
//   c1 = 0.5*x@W1 + b1   (fp32 in ws, via 3-term split-bf16 MFMA GEMM)
//   50x: u1 = 0.5*(u1 + d1*(c1 + W2·r2));  u2 = 0.5*(u2 + d2*(r1@W2 + b2))
//   out = sigmoid(u2)
// Settle v13 = v9 (best passing, settle 514us) + TWO row-groups per block:
// block owns 32 rows (A,B). Per step: A.ph1,A.ph2,B.ph1,B.ph2 | bar |
// u2(A and B on 320 lanes) | bar. Barriers + serial-u2 window now amortized
// over 2x rows (R11 lesson: kernel is latency/barrier-bound — VALU diet made
// it SLOWER at lower VALUBusy). W2 frags shared between groups; hi/lo slabs
// reused serially A-then-B (wave-private, in-order LDS — R3-verified).
// Per-group numerics are op-for-op v9 -> absmax 0.00390625.
// ---------------------------------------------------------------------------

typedef __attribute__((ext_vector_type(8))) short bf16x8;
typedef __attribute__((ext_vector_type(4))) float f32x4;

#define D_IN  784
#define KPAD  800
#define HID   1024
#define D_OUT 10

__device__ __forceinline__ uint32_t fbits(float f){ union{float f;uint32_t u;}v; v.f=f; return v.u; }
__device__ __forceinline__ float asf(uint32_t u){ union{uint32_t u;float f;}v; v.u=u; return v.f; }
__device__ __forceinline__ unsigned short f2bf(float f){ __hip_bfloat16 h=__float2bfloat16(f); return *reinterpret_cast<unsigned short*>(&h); }
__device__ __forceinline__ uint32_t pack2(unsigned short a, unsigned short b){ return (uint32_t)a | ((uint32_t)b<<16); }
__device__ __forceinline__ float sigmoidf_(float x){ return __builtin_amdgcn_rcpf(1.0f + __expf(-x)); }
__device__ __forceinline__ uint32_t cvtpk_bf16(float a, float b){
    uint32_t d;
    asm("v_cvt_pk_bf16_f32 %0, %1, %2" : "=v"(d) : "v"(a), "v"(b));
    return d;   // lo16 = bf16_rne(a), hi16 = bf16_rne(b)
}

// ---------------- prep: W1 (f32 [784][1024]) -> W1^T hi/lo bf16 [1024][800]
__global__ void prep_w1t(const float* __restrict__ W1,
                         unsigned short* __restrict__ w1h, unsigned short* __restrict__ w1l) {
    __shared__ float tile[32][33];
    int kt = blockIdx.x % 25;
    int nt = blockIdx.x / 25;
    int t  = threadIdx.x;
    int kk = t / 8;
    int nn = (t % 8) * 4;
    int k  = kt * 32 + kk;
    float4 v = make_float4(0.f, 0.f, 0.f, 0.f);
    if (k < D_IN)
        v = *reinterpret_cast<const float4*>(W1 + (size_t)k * HID + nt * 32 + nn);
    tile[kk][nn + 0] = v.x; tile[kk][nn + 1] = v.y;
    tile[kk][nn + 2] = v.z; tile[kk][nn + 3] = v.w;
    __syncthreads();
    int nn2 = t / 8;
    int kk2 = (t % 8) * 4;
    unsigned short hs[4], ls[4];
#pragma unroll
    for (int i = 0; i < 4; i++) {
        float f = tile[kk2 + i][nn2];
        uint32_t hb = fbits(f) & 0xffff0000u;
        hs[i] = (unsigned short)(hb >> 16);
        ls[i] = f2bf(f - asf(hb));
    }
    size_t o = (size_t)(nt * 32 + nn2) * KPAD + kt * 32 + kk2;
    uint2 hv; hv.x = pack2(hs[0], hs[1]); hv.y = pack2(hs[2], hs[3]);
    uint2 lv; lv.x = pack2(ls[0], ls[1]); lv.y = pack2(ls[2], ls[3]);
    *reinterpret_cast<uint2*>(w1h + o) = hv;
    *reinterpret_cast<uint2*>(w1l + o) = lv;
}

// ---------------- GEMM: c1 = fp32(0.5*x@W1 + b1)   [16384][1024] f32
__global__ __launch_bounds__(256) void gemm_c1(
    const float* __restrict__ x,
    const unsigned short* __restrict__ w1h, const unsigned short* __restrict__ w1l,
    const float* __restrict__ b1, float* __restrict__ c1)
{
    __shared__ unsigned short Ah[128][40];
    __shared__ unsigned short Al[128][40];
    __shared__ unsigned short Bh[128][40];
    __shared__ unsigned short Bl[128][40];
    int bm = blockIdx.x >> 3;
    int bn = blockIdx.x & 7;
    int t = threadIdx.x;
    int lane = t & 63;
    int wid  = t >> 6;
    int r = lane & 15, g = lane >> 4;
    int wm = wid >> 1, wn = wid & 1;

    f32x4 acc[4][4];
    f32x4 zero = {0.f, 0.f, 0.f, 0.f};
#pragma unroll
    for (int i = 0; i < 4; i++)
#pragma unroll
        for (int j = 0; j < 4; j++) acc[i][j] = zero;

    int srow  = t >> 1;
    int skoff = (t & 1) * 16;
    const float* xbase = x + (size_t)(bm * 128 + srow) * D_IN;
    const unsigned short* bhp = w1h + (size_t)(bn * 128 + srow) * KPAD + skoff;
    const unsigned short* blp = w1l + (size_t)(bn * 128 + srow) * KPAD + skoff;

    for (int kt = 0; kt < KPAD / 32; kt++) {
        int k0 = kt * 32 + skoff;
        float xv[16];
        if (k0 < D_IN) {
#pragma unroll
            for (int c = 0; c < 4; c++) {
                float4 f = *reinterpret_cast<const float4*>(xbase + k0 + 4 * c);
                xv[4*c+0]=f.x; xv[4*c+1]=f.y; xv[4*c+2]=f.z; xv[4*c+3]=f.w;
            }
        } else {
#pragma unroll
            for (int i = 0; i < 16; i++) xv[i] = 0.f;
        }
        uint4 vbh0 = *reinterpret_cast<const uint4*>(bhp + kt * 32);
        uint4 vbh1 = *reinterpret_cast<const uint4*>(bhp + kt * 32 + 8);
        uint4 vbl0 = *reinterpret_cast<const uint4*>(blp + kt * 32);
        uint4 vbl1 = *reinterpret_cast<const uint4*>(blp + kt * 32 + 8);
        uint32_t hw[8], lw[8];
#pragma unroll
        for (int j = 0; j < 8; j++) {
            float f0 = xv[2*j], f1 = xv[2*j+1];
            uint32_t hb0 = fbits(f0) & 0xffff0000u;
            uint32_t hb1 = fbits(f1) & 0xffff0000u;
            hw[j] = (hb0 >> 16) | hb1;
            lw[j] = pack2(f2bf(f0 - asf(hb0)), f2bf(f1 - asf(hb1)));
        }
        __syncthreads();
        *reinterpret_cast<uint4*>(&Ah[srow][skoff])     = make_uint4(hw[0],hw[1],hw[2],hw[3]);
        *reinterpret_cast<uint4*>(&Ah[srow][skoff + 8]) = make_uint4(hw[4],hw[5],hw[6],hw[7]);
        *reinterpret_cast<uint4*>(&Al[srow][skoff])     = make_uint4(lw[0],lw[1],lw[2],lw[3]);
        *reinterpret_cast<uint4*>(&Al[srow][skoff + 8]) = make_uint4(lw[4],lw[5],lw[6],lw[7]);
        *reinterpret_cast<uint4*>(&Bh[srow][skoff])     = vbh0;
        *reinterpret_cast<uint4*>(&Bh[srow][skoff + 8]) = vbh1;
        *reinterpret_cast<uint4*>(&Bl[srow][skoff])     = vbl0;
        *reinterpret_cast<uint4*>(&Bl[srow][skoff + 8]) = vbl1;
        __syncthreads();
        bf16x8 ah[4], al[4], bh[4], bl[4];
#pragma unroll
        for (int mt = 0; mt < 4; mt++) {
            ah[mt] = *reinterpret_cast<const bf16x8*>(&Ah[wm * 64 + mt * 16 + r][g * 8]);
            al[mt] = *reinterpret_cast<const bf16x8*>(&Al[wm * 64 + mt * 16 + r][g * 8]);
        }
#pragma unroll
        for (int nt = 0; nt < 4; nt++) {
            bh[nt] = *reinterpret_cast<const bf16x8*>(&Bh[wn * 64 + nt * 16 + r][g * 8]);
            bl[nt] = *reinterpret_cast<const bf16x8*>(&Bl[wn * 64 + nt * 16 + r][g * 8]);
        }
#pragma unroll
        for (int mt = 0; mt < 4; mt++)
#pragma unroll
            for (int nt = 0; nt < 4; nt++) {
                acc[mt][nt] = __builtin_amdgcn_mfma_f32_16x16x32_bf16(ah[mt], bh[nt], acc[mt][nt], 0, 0, 0);
                acc[mt][nt] = __builtin_amdgcn_mfma_f32_16x16x32_bf16(al[mt], bh[nt], acc[mt][nt], 0, 0, 0);
                acc[mt][nt] = __builtin_amdgcn_mfma_f32_16x16x32_bf16(ah[mt], bl[nt], acc[mt][nt], 0, 0, 0);
            }
    }
#pragma unroll
    for (int nt = 0; nt < 4; nt++) {
        int n = bn * 128 + wn * 64 + nt * 16 + r;
        float bias = b1[n];
#pragma unroll
        for (int mt = 0; mt < 4; mt++) {
            int mrow = bm * 128 + wm * 64 + mt * 16 + g * 4;
#pragma unroll
            for (int q = 0; q < 4; q++)
                c1[(size_t)(mrow + q) * HID + n] = 0.5f * acc[mt][nt][q] + bias;
        }
    }
}

// ---------------- fused settle v13: 1 block = 32 rows (A,B), 16 waves x 64 h.
__global__ __launch_bounds__(1024, 4) void settle(
    const float* __restrict__ u1g, const float* __restrict__ u2g,
    const float* __restrict__ W2,  const float* __restrict__ b2,
    const float* __restrict__ c1,  const int* __restrict__ steps_ptr,
    float* __restrict__ out)
{
    __shared__ unsigned short r1hi[16][16][64];        // 32 KB, shared A-then-B
    __shared__ unsigned short r1lo[16][16][64];        // 32 KB
    __shared__ __align__(16) float s_partA[16][10][20];  // 12.8 KB
    __shared__ __align__(16) float s_partB[16][10][20];  // 12.8 KB
    __shared__ __align__(16) unsigned short r2pA[16][40]; // 1.28 KB
    __shared__ __align__(16) unsigned short r2pB[16][40]; // 1.28 KB

    int t = threadIdx.x;
    int w = t >> 6, lane = t & 63;
    int r = lane & 15, g = lane >> 4;
    int row0 = blockIdx.x * 32;           // rows A: row0..+15, B: row0+16..+31
    int h0 = w * 64;

    // --- u2 state in registers: 320 lanes, two groups of 160 ---
    int tg  = (t >= 160) ? 1 : 0;
    int tb  = t - tg * 160;
    int rr2 = tb / 10, k2 = tb - rr2 * 10;
    float uo = 0.f, r2o = 0.f, b2k = 0.f;
    unsigned short* r2p_my = tg ? &r2pB[0][0] : &r2pA[0][0];
    const float*    sp_my  = tg ? &s_partB[0][0][0] : &s_partA[0][0][0];
    if (t < 320) {
        r2p_my[rr2 * 40 + 30 + (tb % 10)] = 0;   // zero pad slots 30..39
        uo = u2g[(size_t)(row0 + tg * 16 + rr2) * D_OUT + k2];
        r2o = sigmoidf_(uo);
        b2k = b2[k2];
        uint32_t hb = fbits(r2o) & 0xffff0000u;
        unsigned short hi = (unsigned short)(hb >> 16);
        r2p_my[rr2 * 40 + k2] = hi; r2p_my[rr2 * 40 + k2 + 10] = hi;
        r2p_my[rr2 * 40 + k2 + 20] = f2bf(r2o - asf(hb));
    }

    // per-lane fp32 state, both groups (row r / row 16+r, h = h0 + tt*16 + 4g)
    f32x4 u1fA[4], c1fA[4], u1fB[4], c1fB[4];
#pragma unroll
    for (int tt = 0; tt < 4; tt++) {
        int h = h0 + tt * 16 + 4 * g;
        u1fA[tt] = *reinterpret_cast<const f32x4*>(u1g + (size_t)(row0 + r) * HID + h);
        c1fA[tt] = *reinterpret_cast<const f32x4*>(c1  + (size_t)(row0 + r) * HID + h);
        u1fB[tt] = *reinterpret_cast<const f32x4*>(u1g + (size_t)(row0 + 16 + r) * HID + h);
        c1fB[tt] = *reinterpret_cast<const f32x4*>(c1  + (size_t)(row0 + 16 + r) * HID + h);
    }

    // W2 fragments — SHARED between groups (depend only on h).
    // phase-1 A frags: K-slots [W2hi(10) | W2lo(10) | W2hi(10) | 0,0]
    bf16x8 aW2[4];
#pragma unroll
    for (int tt = 0; tt < 4; tt++) {
        int h = h0 + tt * 16 + r;
#pragma unroll
        for (int j = 0; j < 8; j++) {
            int s = 8 * g + j;
            unsigned short val = 0;
            if (s < 30) {
                int k = (s < 10) ? s : (s < 20 ? s - 10 : s - 20);
                float f = W2[(size_t)h * D_OUT + k];
                uint32_t hb = fbits(f) & 0xffff0000u;
                val = (s >= 10 && s < 20) ? f2bf(f - asf(hb)) : (unsigned short)(hb >> 16);
            }
            aW2[tt][j] = (short)val;
        }
    }
    // phase-2 B frags: hi (trunc) and lo (RNE residual)
    bf16x8 bWh[2], bWl[2];
#pragma unroll
    for (int kt = 0; kt < 2; kt++)
#pragma unroll
        for (int j = 0; j < 8; j++) {
            unsigned short vh = 0, vl = 0;
            if (r < D_OUT) {
                int h = h0 + kt * 32 + 8 * g + j;
                float f = W2[(size_t)h * D_OUT + r];
                uint32_t hb = fbits(f) & 0xffff0000u;
                vh = (unsigned short)(hb >> 16);
                vl = f2bf(f - asf(hb));
            }
            bWh[kt][j] = (short)vh; bWl[kt][j] = (short)vl;
        }

    const f32x4 zero = {0.f, 0.f, 0.f, 0.f};
    int steps = steps_ptr[0];

    // typed slab pointers: idx in uint2 units; swizzle = XOR with r (bits 0..3)
    uint2* hiw = reinterpret_cast<uint2*>(&r1hi[w][r][0]);
    uint2* low = reinterpret_cast<uint2*>(&r1lo[w][r][0]);
    const bf16x8* r2rowA = reinterpret_cast<const bf16x8*>(&r2pA[0][0]);  // 16B units, row=5
    const bf16x8* r2rowB = reinterpret_cast<const bf16x8*>(&r2pB[0][0]);

    __syncthreads();

// Per-group step body (op-for-op v9): phase 1 then phase 2.
// Slabs are consumed by this group's phase 2 before the next group's phase 1
// overwrites them (wave-private region, in-order LDS within a wave).
#define GROUP_STEP(U1F, C1F, R2ROW, SPART)                                        \
    {                                                                             \
        bf16x8 br2 = R2ROW[r * 5 + g];                                            \
        _Pragma("unroll")                                                         \
        for (int tt = 0; tt < 4; tt++) {                                          \
            f32x4 m1 = __builtin_amdgcn_mfma_f32_16x16x32_bf16(aW2[tt], br2, C1F[tt], 0, 0, 0); \
            f32x4 u = U1F[tt], un;                                                \
            float rv[4], lof[4];                                                  \
            _Pragma("unroll")                                                     \
            for (int q = 0; q < 4; q++) {                                         \
                rv[q] = sigmoidf_(u[q]);                                          \
                lof[q] = rv[q] - asf(fbits(rv[q]) & 0xffff0000u);                 \
                float d1 = __builtin_fmaf(-rv[q], rv[q], rv[q]);                  \
                un[q] = 0.5f * __builtin_fmaf(d1, m1[q], u[q]);                   \
            }                                                                     \
            U1F[tt] = un;                                                         \
            uint2 hv, lv;                                                         \
            hv.x = __builtin_amdgcn_perm(fbits(rv[1]), fbits(rv[0]), 0x07060302u);\
            hv.y = __builtin_amdgcn_perm(fbits(rv[3]), fbits(rv[2]), 0x07060302u);\
            lv.x = cvtpk_bf16(lof[0], lof[1]);                                    \
            lv.y = cvtpk_bf16(lof[2], lof[3]);                                    \
            hiw[(4 * tt + g) ^ r] = hv;                                           \
            low[(4 * tt + g) ^ r] = lv;                                           \
        }                                                                         \
        f32x4 sa, sb;                                                             \
        {                                                                         \
            union { uint2 p[2]; bf16x8 v; } a0, l0, a1, l1;                       \
            a0.p[0] = hiw[(2 * g)     ^ r]; a0.p[1] = hiw[(2 * g + 1) ^ r];       \
            l0.p[0] = low[(2 * g)     ^ r]; l0.p[1] = low[(2 * g + 1) ^ r];       \
            a1.p[0] = hiw[(8 + 2 * g) ^ r]; a1.p[1] = hiw[(8 + 2 * g + 1) ^ r];   \
            l1.p[0] = low[(8 + 2 * g) ^ r]; l1.p[1] = low[(8 + 2 * g + 1) ^ r];   \
            sa = __builtin_amdgcn_mfma_f32_16x16x32_bf16(a0.v, bWh[0], zero, 0, 0, 0); \
            sb = __builtin_amdgcn_mfma_f32_16x16x32_bf16(a1.v, bWh[1], zero, 0, 0, 0); \
            sa = __builtin_amdgcn_mfma_f32_16x16x32_bf16(l0.v, bWh[0], sa, 0, 0, 0);   \
            sb = __builtin_amdgcn_mfma_f32_16x16x32_bf16(l1.v, bWh[1], sb, 0, 0, 0);   \
            sa = __builtin_amdgcn_mfma_f32_16x16x32_bf16(a0.v, bWl[0], sa, 0, 0, 0);   \
            sb = __builtin_amdgcn_mfma_f32_16x16x32_bf16(a1.v, bWl[1], sb, 0, 0, 0);   \
        }                                                                         \
        f32x4 sc = sa + sb;                                                       \
        if (r < D_OUT) {                                                          \
            int ws = w ^ g;                                                       \
            _Pragma("unroll")                                                     \
            for (int q = 0; q < 4; q++) SPART[4 * g + q][r][ws] = sc[q];          \
        }                                                                         \
    }

    for (int s = 0; s < steps; s++) {
        GROUP_STEP(u1fA, c1fA, r2rowA, s_partA)
        GROUP_STEP(u1fB, c1fB, r2rowB, s_partB)
        __syncthreads();   // BARRIER 1: both groups' s_part visible
        // ---- u2 phase: 320 lanes, both groups in parallel (register state)
        if (t < 320) {
            const f32x4* sp = reinterpret_cast<const f32x4*>(sp_my + rr2 * 200 + k2 * 20);
            f32x4 v0 = sp[0], v1 = sp[1], v2 = sp[2], v3 = sp[3];
            f32x4 vs = (v0 + v1) + (v2 + v3);
            float sv = b2k + ((vs[0] + vs[1]) + (vs[2] + vs[3]));
            float d2 = __builtin_fmaf(-r2o, r2o, r2o);   // r2o = sigmoid(OLD u2)
            uo = 0.5f * __builtin_fmaf(d2, sv, uo);
            r2o = sigmoidf_(uo);
            uint32_t hb = fbits(r2o) & 0xffff0000u;
            unsigned short hi = (unsigned short)(hb >> 16);
            r2p_my[rr2 * 40 + k2] = hi; r2p_my[rr2 * 40 + k2 + 10] = hi;
            r2p_my[rr2 * 40 + k2 + 20] = f2bf(r2o - asf(hb));
        }
        __syncthreads();   // BARRIER 2: r2p updates visible for next step
    }
#undef GROUP_STEP

    if (t < 320)
        out[(size_t)(row0 + tg * 16 + rr2) * D_OUT + k2] = r2o;   // sigmoid(u2_final)
}

// ---------------------------------------------------------------------------
extern "C" void kernel_launch(void* const* d_in, const int* in_sizes, int n_in,
                              void* d_out, int out_size, void* d_ws, size_t ws_size,
                              hipStream_t stream) {
    const float* x   = (const float*)d_in[0];
    const float* u1  = (const float*)d_in[1];
    const float* u2  = (const float*)d_in[2];
    const float* W1  = (const float*)d_in[3];
    const float* W2  = (const float*)d_in[4];
    const float* b1  = (const float*)d_in[5];
    const float* b2  = (const float*)d_in[6];
    const int* steps = (const int*)d_in[7];
    float* out = (float*)d_out;

    // ws layout (~70.4 MB):
    //   [0)         c1  f32  [16384][1024]  67,108,864 B
    //   [67108864)  w1h bf16 [1024][800]     1,638,400 B
    //   [68747264)  w1l bf16 [1024][800]     1,638,400 B
    char* ws = (char*)d_ws;
    float* c1           = (float*)(ws);
    unsigned short* w1h = (unsigned short*)(ws + 67108864u);
    unsigned short* w1l = (unsigned short*)(ws + 67108864u + 1638400u);

    prep_w1t<<<800,  256, 0, stream>>>(W1, w1h, w1l);
    gemm_c1 <<<1024, 256, 0, stream>>>(x, w1h, w1l, b1, c1);
    settle  <<<512,  1024, 0, stream>>>(u1, u2, W2, b2, c1, steps, out);
}

// Round 13
// 571.344 us; speedup vs baseline: 2.9249x; 2.9249x over previous
//
#include <hip/hip_runtime.h>
#include <hip/hip_bf16.h>
#include <stdint.h>

// ---------------------------------------------------------------------------
// EquilibriumPropagationNet free-phase settle, fused, split-bf16 precision.
//   c1 = 0.5*x@W1 + b1   (fp32 in ws, via 3-term split-bf16 MFMA GEMM)
//   50x: u1 = 0.5*(u1 + d1*(c1 + W2·r2));  u2 = 0.5*(u2 + d2*(r1@W2 + b2))
//   out = sigmoid(u2)
// FINAL = Round-7 kernel VERBATIM (passed: total 572.7us, settle 514us,
// absmax 0.00390625). Settle v9: 16 waves x 64 h, full hi/lo split state
// (R5: W2^T W2 ~ 1024*I amplifies state quantization ~10-100x -> state must
// stay exact to ~2^-16). Floor triangulated: issue ~300us (VALUBusy 60%,
// 3 structures), TLP null (R6), VALU diet slower (R11, latency-bound),
// overlap/barrier levers negative (R4/R11), row-doubling spills (R12 —
// u1+c1 state = 128MB = the chip's ENTIRE VGPR file; 1 block/CU is forced).
// ---------------------------------------------------------------------------

typedef __attribute__((ext_vector_type(8))) short bf16x8;
typedef __attribute__((ext_vector_type(4))) float f32x4;

#define D_IN  784
#define KPAD  800
#define HID   1024
#define D_OUT 10

__device__ __forceinline__ uint32_t fbits(float f){ union{float f;uint32_t u;}v; v.f=f; return v.u; }
__device__ __forceinline__ float asf(uint32_t u){ union{uint32_t u;float f;}v; v.u=u; return v.f; }
__device__ __forceinline__ unsigned short f2bf(float f){ __hip_bfloat16 h=__float2bfloat16(f); return *reinterpret_cast<unsigned short*>(&h); }
__device__ __forceinline__ uint32_t pack2(unsigned short a, unsigned short b){ return (uint32_t)a | ((uint32_t)b<<16); }
__device__ __forceinline__ float sigmoidf_(float x){ return __builtin_amdgcn_rcpf(1.0f + __expf(-x)); }
__device__ __forceinline__ uint32_t cvtpk_bf16(float a, float b){
    uint32_t d;
    asm("v_cvt_pk_bf16_f32 %0, %1, %2" : "=v"(d) : "v"(a), "v"(b));
    return d;   // lo16 = bf16_rne(a), hi16 = bf16_rne(b)
}

// ---------------- prep: W1 (f32 [784][1024]) -> W1^T hi/lo bf16 [1024][800]
__global__ void prep_w1t(const float* __restrict__ W1,
                         unsigned short* __restrict__ w1h, unsigned short* __restrict__ w1l) {
    __shared__ float tile[32][33];
    int kt = blockIdx.x % 25;
    int nt = blockIdx.x / 25;
    int t  = threadIdx.x;
    int kk = t / 8;
    int nn = (t % 8) * 4;
    int k  = kt * 32 + kk;
    float4 v = make_float4(0.f, 0.f, 0.f, 0.f);
    if (k < D_IN)
        v = *reinterpret_cast<const float4*>(W1 + (size_t)k * HID + nt * 32 + nn);
    tile[kk][nn + 0] = v.x; tile[kk][nn + 1] = v.y;
    tile[kk][nn + 2] = v.z; tile[kk][nn + 3] = v.w;
    __syncthreads();
    int nn2 = t / 8;
    int kk2 = (t % 8) * 4;
    unsigned short hs[4], ls[4];
#pragma unroll
    for (int i = 0; i < 4; i++) {
        float f = tile[kk2 + i][nn2];
        uint32_t hb = fbits(f) & 0xffff0000u;
        hs[i] = (unsigned short)(hb >> 16);
        ls[i] = f2bf(f - asf(hb));
    }
    size_t o = (size_t)(nt * 32 + nn2) * KPAD + kt * 32 + kk2;
    uint2 hv; hv.x = pack2(hs[0], hs[1]); hv.y = pack2(hs[2], hs[3]);
    uint2 lv; lv.x = pack2(ls[0], ls[1]); lv.y = pack2(ls[2], ls[3]);
    *reinterpret_cast<uint2*>(w1h + o) = hv;
    *reinterpret_cast<uint2*>(w1l + o) = lv;
}

// ---------------- GEMM: c1 = fp32(0.5*x@W1 + b1)   [16384][1024] f32
__global__ __launch_bounds__(256) void gemm_c1(
    const float* __restrict__ x,
    const unsigned short* __restrict__ w1h, const unsigned short* __restrict__ w1l,
    const float* __restrict__ b1, float* __restrict__ c1)
{
    __shared__ unsigned short Ah[128][40];
    __shared__ unsigned short Al[128][40];
    __shared__ unsigned short Bh[128][40];
    __shared__ unsigned short Bl[128][40];
    int bm = blockIdx.x >> 3;
    int bn = blockIdx.x & 7;
    int t = threadIdx.x;
    int lane = t & 63;
    int wid  = t >> 6;
    int r = lane & 15, g = lane >> 4;
    int wm = wid >> 1, wn = wid & 1;

    f32x4 acc[4][4];
    f32x4 zero = {0.f, 0.f, 0.f, 0.f};
#pragma unroll
    for (int i = 0; i < 4; i++)
#pragma unroll
        for (int j = 0; j < 4; j++) acc[i][j] = zero;

    int srow  = t >> 1;
    int skoff = (t & 1) * 16;
    const float* xbase = x + (size_t)(bm * 128 + srow) * D_IN;
    const unsigned short* bhp = w1h + (size_t)(bn * 128 + srow) * KPAD + skoff;
    const unsigned short* blp = w1l + (size_t)(bn * 128 + srow) * KPAD + skoff;

    for (int kt = 0; kt < KPAD / 32; kt++) {
        int k0 = kt * 32 + skoff;
        float xv[16];
        if (k0 < D_IN) {
#pragma unroll
            for (int c = 0; c < 4; c++) {
                float4 f = *reinterpret_cast<const float4*>(xbase + k0 + 4 * c);
                xv[4*c+0]=f.x; xv[4*c+1]=f.y; xv[4*c+2]=f.z; xv[4*c+3]=f.w;
            }
        } else {
#pragma unroll
            for (int i = 0; i < 16; i++) xv[i] = 0.f;
        }
        uint4 vbh0 = *reinterpret_cast<const uint4*>(bhp + kt * 32);
        uint4 vbh1 = *reinterpret_cast<const uint4*>(bhp + kt * 32 + 8);
        uint4 vbl0 = *reinterpret_cast<const uint4*>(blp + kt * 32);
        uint4 vbl1 = *reinterpret_cast<const uint4*>(blp + kt * 32 + 8);
        uint32_t hw[8], lw[8];
#pragma unroll
        for (int j = 0; j < 8; j++) {
            float f0 = xv[2*j], f1 = xv[2*j+1];
            uint32_t hb0 = fbits(f0) & 0xffff0000u;
            uint32_t hb1 = fbits(f1) & 0xffff0000u;
            hw[j] = (hb0 >> 16) | hb1;
            lw[j] = pack2(f2bf(f0 - asf(hb0)), f2bf(f1 - asf(hb1)));
        }
        __syncthreads();
        *reinterpret_cast<uint4*>(&Ah[srow][skoff])     = make_uint4(hw[0],hw[1],hw[2],hw[3]);
        *reinterpret_cast<uint4*>(&Ah[srow][skoff + 8]) = make_uint4(hw[4],hw[5],hw[6],hw[7]);
        *reinterpret_cast<uint4*>(&Al[srow][skoff])     = make_uint4(lw[0],lw[1],lw[2],lw[3]);
        *reinterpret_cast<uint4*>(&Al[srow][skoff + 8]) = make_uint4(lw[4],lw[5],lw[6],lw[7]);
        *reinterpret_cast<uint4*>(&Bh[srow][skoff])     = vbh0;
        *reinterpret_cast<uint4*>(&Bh[srow][skoff + 8]) = vbh1;
        *reinterpret_cast<uint4*>(&Bl[srow][skoff])     = vbl0;
        *reinterpret_cast<uint4*>(&Bl[srow][skoff + 8]) = vbl1;
        __syncthreads();
        bf16x8 ah[4], al[4], bh[4], bl[4];
#pragma unroll
        for (int mt = 0; mt < 4; mt++) {
            ah[mt] = *reinterpret_cast<const bf16x8*>(&Ah[wm * 64 + mt * 16 + r][g * 8]);
            al[mt] = *reinterpret_cast<const bf16x8*>(&Al[wm * 64 + mt * 16 + r][g * 8]);
        }
#pragma unroll
        for (int nt = 0; nt < 4; nt++) {
            bh[nt] = *reinterpret_cast<const bf16x8*>(&Bh[wn * 64 + nt * 16 + r][g * 8]);
            bl[nt] = *reinterpret_cast<const bf16x8*>(&Bl[wn * 64 + nt * 16 + r][g * 8]);
        }
#pragma unroll
        for (int mt = 0; mt < 4; mt++)
#pragma unroll
            for (int nt = 0; nt < 4; nt++) {
                acc[mt][nt] = __builtin_amdgcn_mfma_f32_16x16x32_bf16(ah[mt], bh[nt], acc[mt][nt], 0, 0, 0);
                acc[mt][nt] = __builtin_amdgcn_mfma_f32_16x16x32_bf16(al[mt], bh[nt], acc[mt][nt], 0, 0, 0);
                acc[mt][nt] = __builtin_amdgcn_mfma_f32_16x16x32_bf16(ah[mt], bl[nt], acc[mt][nt], 0, 0, 0);
            }
    }
#pragma unroll
    for (int nt = 0; nt < 4; nt++) {
        int n = bn * 128 + wn * 64 + nt * 16 + r;
        float bias = b1[n];
#pragma unroll
        for (int mt = 0; mt < 4; mt++) {
            int mrow = bm * 128 + wm * 64 + mt * 16 + g * 4;
#pragma unroll
            for (int q = 0; q < 4; q++)
                c1[(size_t)(mrow + q) * HID + n] = 0.5f * acc[mt][nt][q] + bias;
        }
    }
}

// ---------------- fused settle v9: 1 block = 16 rows, 16 waves x 64 h.
__global__ __launch_bounds__(1024, 4) void settle(
    const float* __restrict__ u1g, const float* __restrict__ u2g,
    const float* __restrict__ W2,  const float* __restrict__ b2,
    const float* __restrict__ c1,  const int* __restrict__ steps_ptr,
    float* __restrict__ out)
{
    __shared__ unsigned short r1hi[16][16][64];   // 32 KB [wave][row][h-local]
    __shared__ unsigned short r1lo[16][16][64];   // 32 KB
    __shared__ float s_part[16][10][20];          // 12.8 KB [row][k][slot], slot = w^g
    __shared__ unsigned short r2p[16][40];        // 80B/row: [hi10|hi10|lo10|0(10)]

    int t = threadIdx.x;
    int w = t >> 6, lane = t & 63;
    int r = lane & 15, g = lane >> 4;
    int row0 = blockIdx.x * 16;
    int h0 = w * 64;

    // --- u2 state lives in the u2-lanes' registers (t<160) ---
    int rr2 = t / 10, k2 = t - rr2 * 10;
    float uo = 0.f, r2o = 0.f, b2k = 0.f;
    if (t < 160) { int i = t; r2p[rr2][30 + (i % 10)] = 0; }  // zero pad slots 30..39
    if (t < 160) {
        uo = u2g[(size_t)(row0 + rr2) * D_OUT + k2];
        r2o = sigmoidf_(uo);
        b2k = b2[k2];
        uint32_t hb = fbits(r2o) & 0xffff0000u;
        unsigned short hi = (unsigned short)(hb >> 16);
        r2p[rr2][k2] = hi; r2p[rr2][k2 + 10] = hi;
        r2p[rr2][k2 + 20] = f2bf(r2o - asf(hb));
    }

    // per-lane fp32 state: u1, c1 (row r, h = h0 + tt*16 + 4g + q)
    f32x4 u1f[4], c1f[4];
#pragma unroll
    for (int tt = 0; tt < 4; tt++) {
        int h = h0 + tt * 16 + 4 * g;
        u1f[tt] = *reinterpret_cast<const f32x4*>(u1g + (size_t)(row0 + r) * HID + h);
        c1f[tt] = *reinterpret_cast<const f32x4*>(c1  + (size_t)(row0 + r) * HID + h);
    }

    // phase-1 A frags: K-slots [W2hi(10) | W2lo(10) | W2hi(10) | 0,0]
    bf16x8 aW2[4];
#pragma unroll
    for (int tt = 0; tt < 4; tt++) {
        int h = h0 + tt * 16 + r;
#pragma unroll
        for (int j = 0; j < 8; j++) {
            int s = 8 * g + j;
            unsigned short val = 0;
            if (s < 30) {
                int k = (s < 10) ? s : (s < 20 ? s - 10 : s - 20);
                float f = W2[(size_t)h * D_OUT + k];
                uint32_t hb = fbits(f) & 0xffff0000u;
                val = (s >= 10 && s < 20) ? f2bf(f - asf(hb)) : (unsigned short)(hb >> 16);
            }
            aW2[tt][j] = (short)val;
        }
    }
    // phase-2 B frags: hi (trunc) and lo (RNE residual)
    bf16x8 bWh[2], bWl[2];
#pragma unroll
    for (int kt = 0; kt < 2; kt++)
#pragma unroll
        for (int j = 0; j < 8; j++) {
            unsigned short vh = 0, vl = 0;
            if (r < D_OUT) {
                int h = h0 + kt * 32 + 8 * g + j;
                float f = W2[(size_t)h * D_OUT + r];
                uint32_t hb = fbits(f) & 0xffff0000u;
                vh = (unsigned short)(hb >> 16);
                vl = f2bf(f - asf(hb));
            }
            bWh[kt][j] = (short)vh; bWl[kt][j] = (short)vl;
        }

    const f32x4 zero = {0.f, 0.f, 0.f, 0.f};
    int steps = steps_ptr[0];

    // typed slab pointers: idx in uint2 units; swizzle = XOR with r (bits 0..3)
    uint2* hiw = reinterpret_cast<uint2*>(&r1hi[w][r][0]);
    uint2* low = reinterpret_cast<uint2*>(&r1lo[w][r][0]);
    const bf16x8* r2row = reinterpret_cast<const bf16x8*>(&r2p[0][0]);  // 16B units, row=5

    __syncthreads();

    for (int s = 0; s < steps; s++) {
        // ---- phase 1: m1 = c1 + W2*r2 (exact via K-packing, c1 as C-init);
        //      update u1; write r1 hi(trunc)+lo(RNE) to wave-private slabs.
        bf16x8 br2 = r2row[r * 5 + g];
#pragma unroll
        for (int tt = 0; tt < 4; tt++) {
            f32x4 m1 = __builtin_amdgcn_mfma_f32_16x16x32_bf16(aW2[tt], br2, c1f[tt], 0, 0, 0);
            f32x4 u = u1f[tt], un;
            float rv[4], lof[4];
#pragma unroll
            for (int q = 0; q < 4; q++) {
                rv[q] = sigmoidf_(u[q]);               // r1 from OLD u1 (fp32)
                lof[q] = rv[q] - asf(fbits(rv[q]) & 0xffff0000u);
                float d1 = __builtin_fmaf(-rv[q], rv[q], rv[q]);
                un[q] = 0.5f * __builtin_fmaf(d1, m1[q], u[q]);
            }
            u1f[tt] = un;
            uint2 hv, lv;
            hv.x = __builtin_amdgcn_perm(fbits(rv[1]), fbits(rv[0]), 0x07060302u);
            hv.y = __builtin_amdgcn_perm(fbits(rv[3]), fbits(rv[2]), 0x07060302u);
            lv.x = cvtpk_bf16(lof[0], lof[1]);
            lv.y = cvtpk_bf16(lof[2], lof[3]);
            hiw[(4 * tt + g) ^ r] = hv;
            low[(4 * tt + g) ^ r] = lv;
        }
        // ---- phase 2: s = r1 @ W2, 3 split terms, 2 independent MFMA chains
        f32x4 sa = zero, sb = zero;
        {
            union { uint2 p[2]; bf16x8 v; } a0, l0, a1, l1;
            a0.p[0] = hiw[(2 * g)     ^ r]; a0.p[1] = hiw[(2 * g + 1) ^ r];
            l0.p[0] = low[(2 * g)     ^ r]; l0.p[1] = low[(2 * g + 1) ^ r];
            a1.p[0] = hiw[(8 + 2 * g) ^ r]; a1.p[1] = hiw[(8 + 2 * g + 1) ^ r];
            l1.p[0] = low[(8 + 2 * g) ^ r]; l1.p[1] = low[(8 + 2 * g + 1) ^ r];
            sa = __builtin_amdgcn_mfma_f32_16x16x32_bf16(a0.v, bWh[0], sa, 0, 0, 0);
            sb = __builtin_amdgcn_mfma_f32_16x16x32_bf16(a1.v, bWh[1], sb, 0, 0, 0);
            sa = __builtin_amdgcn_mfma_f32_16x16x32_bf16(l0.v, bWh[0], sa, 0, 0, 0);
            sb = __builtin_amdgcn_mfma_f32_16x16x32_bf16(l1.v, bWh[1], sb, 0, 0, 0);
            sa = __builtin_amdgcn_mfma_f32_16x16x32_bf16(a0.v, bWl[0], sa, 0, 0, 0);
            sb = __builtin_amdgcn_mfma_f32_16x16x32_bf16(a1.v, bWl[1], sb, 0, 0, 0);
        }
        f32x4 sc = sa + sb;
        if (r < D_OUT) {
            int ws = w ^ g;   // bijective slot per (row,k); breaks g-bank aliasing
#pragma unroll
            for (int q = 0; q < 4; q++) s_part[4 * g + q][r][ws] = sc[q];
        }
        __syncthreads();
        // ---- u2 phase (160 lanes, register state, 1 sigmoid, b128 reads)
        if (t < 160) {
            const f32x4* sp = reinterpret_cast<const f32x4*>(&s_part[rr2][k2][0]);
            f32x4 v0 = sp[0], v1 = sp[1], v2 = sp[2], v3 = sp[3];
            f32x4 vs = (v0 + v1) + (v2 + v3);
            float sv = b2k + ((vs[0] + vs[1]) + (vs[2] + vs[3]));
            float d2 = __builtin_fmaf(-r2o, r2o, r2o);   // r2o = sigmoid(OLD u2), cached
            uo = 0.5f * __builtin_fmaf(d2, sv, uo);
            r2o = sigmoidf_(uo);
            uint32_t hb = fbits(r2o) & 0xffff0000u;
            unsigned short hi = (unsigned short)(hb >> 16);
            r2p[rr2][k2] = hi; r2p[rr2][k2 + 10] = hi;
            r2p[rr2][k2 + 20] = f2bf(r2o - asf(hb));
        }
        __syncthreads();
    }

    if (t < 160)
        out[(size_t)(row0 + rr2) * D_OUT + k2] = r2o;   // sigmoid(u2_final), cached

}

// ---------------------------------------------------------------------------
extern "C" void kernel_launch(void* const* d_in, const int* in_sizes, int n_in,
                              void* d_out, int out_size, void* d_ws, size_t ws_size,
                              hipStream_t stream) {
    const float* x   = (const float*)d_in[0];
    const float* u1  = (const float*)d_in[1];
    const float* u2  = (const float*)d_in[2];
    const float* W1  = (const float*)d_in[3];
    const float* W2  = (const float*)d_in[4];
    const float* b1  = (const float*)d_in[5];
    const float* b2  = (const float*)d_in[6];
    const int* steps = (const int*)d_in[7];
    float* out = (float*)d_out;

    // ws layout (~70.4 MB):
    //   [0)         c1  f32  [16384][1024]  67,108,864 B
    //   [67108864)  w1h bf16 [1024][800]     1,638,400 B
    //   [68747264)  w1l bf16 [1024][800]     1,638,400 B
    char* ws = (char*)d_ws;
    float* c1           = (float*)(ws);
    unsigned short* w1h = (unsigned short*)(ws + 67108864u);
    unsigned short* w1l = (unsigned short*)(ws + 67108864u + 1638400u);

    prep_w1t<<<800,  256, 0, stream>>>(W1, w1h, w1l);
    gemm_c1 <<<1024, 256, 0, stream>>>(x, w1h, w1l, b1, c1);
    settle  <<<1024, 1024, 0, stream>>>(u1, u2, W2, b2, c1, steps, out);
}